// Round 4
// baseline (110.359 us; speedup 1.0000x reference)
//
#include <hip/hip_runtime.h>

// SoftRAM attention: S=128, B=256 bits, H=16 heads, NB=12 bits/neuron, PB=7.
// addr(i,j,h,n) = aq_i | ak_j | ap_{i-j}, disjoint bit groups per (h,n).
//
// R12: async LUT-row staging. R11 compiled to 60 VGPRs -> the 16 float4 row
// loads were batch-drained (exposed HBM latency several times per wave, on
// every wave concurrently; softram ~33us vs ~10us/CU fetch floor).
// Now the 16KB row goes HBM -> LDS via __builtin_amdgcn_global_load_lds
// (16B width, zero VGPR cost), 4-slot x 1KB ring per wave, hand-counted
// s_waitcnt vmcnt(3..0) (never 0 mid-loop) + sched_barrier(0) fences.
// Prologue issues 4 tiles right after barrier #1 so mask/class build overlaps
// the first drain; each tile is consumed into the sigma byte-table as it
// lands. Sign-pack hoisted out of the per-path branches (common pipeline).
// Sweeps / repack / pack_kernel / vote_kernel byte-identical to R11
// (verified absmax 0).

#define S 128
#define B 256
#define H 16
#define NB 12

__device__ __forceinline__ unsigned sig(unsigned x) {
    return x ^ ((x >> 3) & 0x70u) ^ ((x >> 6) & 0x70u);
}

// token bit c lives at packed word TW(c), bit TP(c)
#define TW(c) ((((c) & 3) << 1) + ((c) >> 7))
#define TP(c) (((c) >> 2) & 31)

__global__ __launch_bounds__(256) void pack_kernel(
    const int* __restrict__ tokens,        // [S,B] 0/1
    unsigned* __restrict__ tokP)           // [8][S] packed
{
    const int wid  = threadIdx.x >> 6;
    const int lane = threadIdx.x & 63;
    const int4* tp = (const int4*)tokens;
    #pragma unroll
    for (int r = 0; r < 4; ++r) {
        int i = blockIdx.x * 16 + wid * 4 + r;
        int4 x = tp[i * 64 + lane];        // coalesced: full row of 256 ints
        unsigned long long B0 = __ballot((x.x & 1) != 0);  // bit l = tok[4l+0]
        unsigned long long B1 = __ballot((x.y & 1) != 0);
        unsigned long long B2 = __ballot((x.z & 1) != 0);
        unsigned long long B3 = __ballot((x.w & 1) != 0);
        int c = lane >> 1;                 // word index = comp*2 + half
        unsigned long long s01 = (c & 1) ? B1 : B0;
        unsigned long long s23 = (c & 1) ? B3 : B2;
        unsigned long long s   = (c & 2) ? s23 : s01;
        unsigned word = (lane & 1) ? (unsigned)(s >> 32) : (unsigned)s;
        if (lane < 8) tokP[lane * 128 + i] = word;
    }
}

__global__ __launch_bounds__(256, 4) void softram_kernel(
    const unsigned* __restrict__ tokP,     // [8][S] packed tokens
    const float* __restrict__ memory,      // [H,B,4096]
    const int* __restrict__ connections,   // [H,B,NB]
    unsigned char* __restrict__ pc)        // [4][256][128] per-group counts
{
    const int bid  = blockIdx.x;
    const int g    = bid >> 8;             // head group (0..3)
    const int n    = bid & 255;            // neuron
    const int tid  = threadIdx.x;
    const int wid  = tid >> 6;             // wave in block (0..3)
    const int hg   = g * 4 + wid;          // global head
    const int lane = tid & 63;

    __shared__ __align__(16) unsigned char  bytetab[4 * 4096];  // 16 KB signs
    __shared__ __align__(16) float          stage[4][4 * 256];  // 16 KB ring
    __shared__ __align__(16) unsigned int   tokT[8 * S];        // 4 KB packed
    __shared__ __align__(16) unsigned short akT[4][S];          // key class / sig(ak)
    __shared__ __align__(16) unsigned short apt[4][S];          // sig(ap) (fallback)
    __shared__ int            conns[4][NB];
    __shared__ unsigned int   parts[4][4];

    const float* gbase = memory + ((size_t)(hg * 256 + n) << 12);
    float*       sbase = &stage[wid][0];
    unsigned char* __restrict__ bt = &bytetab[wid << 12];

    // ---- stage packed tokens (4KB, coalesced, L2-hot) + conns ----
    ((int4*)tokT)[tid] = ((const int4*)tokP)[tid];
    if (tid < 4 * NB) {
        int hh = tid / NB, b = tid - hh * NB;
        conns[hh][b] = connections[(size_t)(g * 4 + hh) * (B * NB) + n * NB + b];
    }
    __syncthreads();   // barrier #1 (drains all VMEM -> vmcnt==0 here)

    // ---- async row staging: issue 4 tiles (1KB each) into the ring ----
#if __has_builtin(__builtin_amdgcn_global_load_lds)
#define GLLD(T) __builtin_amdgcn_global_load_lds( \
        (const __attribute__((address_space(1))) void*)(gbase + (T) * 256 + lane * 4), \
        (__attribute__((address_space(3))) void*)(sbase + ((T) & 3) * 256), 16, 0, 0)
#else
#define GLLD(T) do { *(float4*)(sbase + ((T) & 3) * 256 + lane * 4) = \
        *(const float4*)(gbase + (T) * 256 + lane * 4); } while (0)
#endif
    GLLD(0); GLLD(1); GLLD(2); GLLD(3);

    // ---- per-head masks (wave-uniform; overlaps first tile's flight) ----
    unsigned qmask = 0, kmask = 0, pmask = 0;
    #pragma unroll
    for (int b = 0; b < NB; ++b) {
        int c = conns[wid][b];
        qmask |= (unsigned)(c < 256) << b;
        kmask |= (unsigned)(c >= 256 && c < 512) << b;
        pmask |= (unsigned)(c >= 512) << b;
    }
    const int qb = __popc(qmask);
    const int kb = __popc(kmask);
    const bool fast = (pmask == 0);

    // ---- path-specific class tables (LDS-only; overlaps load flight) ----
    unsigned qclsA = 0, qclsB = 0;         // fast: query class  | fb: sig(aq)
    if (fast) {
        #pragma unroll
        for (int e = 0; e < 2; ++e) {
            int ii = lane + 64 * e;
            unsigned qc = 0, kc = 0;
            int qn = 0, kn = 0;
            #pragma unroll
            for (int b = 0; b < NB; ++b) {
                int c = conns[wid][b];     // wave-uniform -> uniform branches
                if (c < 256) {
                    qc |= ((tokT[TW(c) * S + ii] >> TP(c)) & 1u) << qn;
                    ++qn;
                } else {
                    int c2 = c - 256;
                    kc |= ((tokT[TW(c2) * S + ii] >> TP(c2)) & 1u) << kn;
                    ++kn;
                }
            }
            akT[wid][ii] = (unsigned short)kc;
            if (e == 0) qclsA = qc; else qclsB = qc;
        }
    } else {
        #pragma unroll
        for (int e = 0; e < 2; ++e) {
            int ii = lane + 64 * e;
            unsigned aq = 0, ak = 0, ap = 0;
            #pragma unroll
            for (int b = 0; b < NB; ++b) {
                int c = conns[wid][b];
                if (c < 256) {
                    aq |= ((tokT[TW(c) * S + ii] >> TP(c)) & 1u) << b;
                } else if (c < 512) {
                    int c2 = c - 256;
                    ak |= ((tokT[TW(c2) * S + ii] >> TP(c2)) & 1u) << b;
                } else {
                    ap |= (((unsigned)ii >> (c - 512)) & 1u) << b;
                }
            }
            akT[wid][ii] = (unsigned short)sig(ak);
            apt[wid][ii] = (unsigned short)sig(ap);
            if (e == 0) qclsA = sig(aq); else qclsB = sig(aq);
        }
    }

    // ---- pipelined consume: wait counted (never 0 mid-loop), pack signs
    //      into sigma-addressed bytes, reissue next tile into freed slot ----
#define STEP(T, NW) do { \
    asm volatile("s_waitcnt vmcnt(" #NW ")" ::: "memory"); \
    __builtin_amdgcn_sched_barrier(0); \
    float4 v = *(const float4*)(sbase + ((T) & 3) * 256 + lane * 4); \
    unsigned w = (unsigned)(v.x > 0.f) \
               | ((unsigned)(v.y > 0.f) << 8) \
               | ((unsigned)(v.z > 0.f) << 16) \
               | ((unsigned)(v.w > 0.f) << 24); \
    asm volatile("s_waitcnt lgkmcnt(0)" ::: "memory"); \
    __builtin_amdgcn_sched_barrier(0); \
    if ((T) + 4 < 16) { GLLD((T) + 4); } \
    *(unsigned*)&bt[sig(4u * (unsigned)(lane + 64 * (T)))] = w; \
} while (0)

    STEP(0, 3);  STEP(1, 3);  STEP(2, 3);  STEP(3, 3);
    STEP(4, 3);  STEP(5, 3);  STEP(6, 3);  STEP(7, 3);
    STEP(8, 3);  STEP(9, 3);  STEP(10, 3); STEP(11, 3);
    STEP(12, 3); STEP(13, 2); STEP(14, 1); STEP(15, 0);
#undef STEP

    unsigned long long rlo = 0, rhi = 0;

    if (fast) {
        // ================= fast path: register bit-LUT =================
        // repack to lane-distributed bit-LUT: lane w holds global bits
        // gbit in [64w, 64w+64), gbit = (Lcls << SBITS) | Scls.
        const bool formA = (qb <= 6);      // bit-side = Q if qb<=6 else K
        const int SBITS  = formA ? qb : kb;
        unsigned apl = 0, aul = 0;
        {
            int scnt = 0, lcnt = 0;
            #pragma unroll
            for (int b = 0; b < NB; ++b) {
                int c = conns[wid][b];
                bool isS = formA ? (c < 256) : (c >= 256);
                if (isS) {
                    apl |= (((unsigned)lane >> scnt) & 1u) << b;
                    ++scnt;
                } else {
                    int p = SBITS + lcnt;
                    if (p < 6) apl |= (((unsigned)lane >> p) & 1u) << b;
                    else       aul |= (((unsigned)lane >> (p - 6)) & 1u) << b;
                    ++lcnt;
                }
            }
        }
        const unsigned spl  = sig(apl);
        const unsigned saul = sig(aul);
        unsigned Wlo = 0, Whi = 0;
        #pragma unroll 8
        for (int it = 0; it < 64; ++it) {
            unsigned sau  = (unsigned)__builtin_amdgcn_readlane((int)saul, it);
            unsigned bitv = bt[sau ^ spl] & 1u;   // sign at gbit = it*64+lane
            unsigned long long Bm = __ballot(bitv != 0u);
#if __has_builtin(__builtin_amdgcn_writelane)
            Wlo = (unsigned)__builtin_amdgcn_writelane((int)(unsigned)Bm, it, (int)Wlo);
            Whi = (unsigned)__builtin_amdgcn_writelane((int)(unsigned)(Bm >> 32), it, (int)Whi);
#else
            Wlo = (lane == it) ? (unsigned)Bm : Wlo;
            Whi = (lane == it) ? (unsigned)(Bm >> 32) : Whi;
#endif
        }
        const unsigned long long Wfull = ((unsigned long long)Whi << 32) | Wlo;

        if (formA) {
            // lane-parallel prefix-XOR over keys. lane j = key j (half 1),
            // key 64+j (half 2). V_j = LUTword(kcls_j) >> (g0_j & 63);
            // prefix_j = XOR_{j'<=j} V_j'; r_i (i=j) = bit qcls_i of prefix_j.
            unsigned kclsA = akT[wid][lane];
            unsigned g0 = kclsA << qb;
            unsigned long long V = __shfl(Wfull, (int)(g0 >> 6)) >> (g0 & 63u);
            #pragma unroll
            for (int d = 1; d < 64; d <<= 1) {
                unsigned long long u = __shfl_up(V, (unsigned)d);
                V ^= (lane >= d) ? u : 0ull;
            }
            rlo = __ballot(((V >> qclsA) & 1ull) != 0ull);
            const unsigned long long Abase = __shfl(V, 63);

            unsigned kclsB = akT[wid][64 + lane];
            unsigned g1 = kclsB << qb;
            unsigned long long V1 = __shfl(Wfull, (int)(g1 >> 6)) >> (g1 & 63u);
            #pragma unroll
            for (int d = 1; d < 64; d <<= 1) {
                unsigned long long u = __shfl_up(V1, (unsigned)d);
                V1 ^= (lane >= d) ? u : 0ull;
            }
            V1 ^= Abase;
            rhi = __ballot(((V1 >> qclsB) & 1ull) != 0ull);
        } else {
            // kb <= 5: prefix-XOR of one-hot key classes (32-bit), then
            // r_i = parity(LUTrow[qcls_i] & prefix_i).
            unsigned kclsA = akT[wid][lane];
            unsigned C = 1u << kclsA;
            #pragma unroll
            for (int d = 1; d < 64; d <<= 1) {
                unsigned u = __shfl_up(C, (unsigned)d);
                C ^= (lane >= d) ? u : 0u;
            }
            unsigned g0a = qclsA << kb;
            unsigned W0 = (unsigned)(__shfl(Wfull, (int)(g0a >> 6)) >> (g0a & 63u));
            rlo = __ballot((__popc(W0 & C) & 1) != 0);
            const unsigned Cbase = __shfl(C, 63);

            unsigned kclsB = akT[wid][64 + lane];
            unsigned C1 = 1u << kclsB;
            #pragma unroll
            for (int d = 1; d < 64; d <<= 1) {
                unsigned u = __shfl_up(C1, (unsigned)d);
                C1 ^= (lane >= d) ? u : 0u;
            }
            C1 ^= Cbase;
            unsigned g0b = qclsB << kb;
            unsigned W1 = (unsigned)(__shfl(Wfull, (int)(g0b >> 6)) >> (g0b & 63u));
            rhi = __ballot((__popc(W1 & C1) & 1) != 0);
        }
    } else {
        // ================= P fallback: lanes = queries =================
        // queries i=lane (acc0) and i=lane+64 (acc1); arithmetic causal masks.
        const unsigned aqv0 = qclsA, aqv1 = qclsB;
        unsigned acc0 = 0, acc1 = 0;
        for (int s8 = 0; s8 < 8; ++s8) {       // j = 0..63
            uint4 uk = *(const uint4*)&akT[wid][s8 * 8];
            #pragma unroll
            for (int t = 0; t < 8; ++t) {
                int j = s8 * 8 + t;
                unsigned w = ((const unsigned*)&uk)[t >> 1];
                unsigned akv = (w >> ((t & 1) * 16)) & 0xffffu;
                int d0 = lane - j;             // <0 -> masked out
                unsigned v0 = bt[aqv0 ^ akv ^ (unsigned)apt[wid][d0 & 127]] & 1u;
                acc0 ^= (d0 >= 0) ? v0 : 0u;
                int d1 = lane + 64 - j;        // in [1,127]: always active
                unsigned v1 = bt[aqv1 ^ akv ^ (unsigned)apt[wid][d1]] & 1u;
                acc1 ^= v1;
            }
        }
        for (int s8 = 8; s8 < 16; ++s8) {      // j = 64..127: only upper query
            uint4 uk = *(const uint4*)&akT[wid][s8 * 8];
            #pragma unroll
            for (int t = 0; t < 8; ++t) {
                int j = s8 * 8 + t;
                unsigned w = ((const unsigned*)&uk)[t >> 1];
                unsigned akv = (w >> ((t & 1) * 16)) & 0xffffu;
                int d1 = lane + 64 - j;        // <0 -> masked out
                unsigned v1 = bt[aqv1 ^ akv ^ (unsigned)apt[wid][d1 & 127]] & 1u;
                acc1 ^= (d1 >= 0) ? v1 : 0u;
            }
        }
        rlo = __ballot(acc0 != 0u);
        rhi = __ballot(acc1 != 0u);
    }

    if (lane == 0) {
        parts[wid][0] = (unsigned)rlo;
        parts[wid][1] = (unsigned)(rlo >> 32);
        parts[wid][2] = (unsigned)rhi;
        parts[wid][3] = (unsigned)(rhi >> 32);
    }
    __syncthreads();   // barrier #2: parts visible

    // ---- per-group count (0..4) per query bit; fully overwrites slot ----
    if (tid < S) {
        int i = tid, tot = 0;
        #pragma unroll
        for (int hh = 0; hh < 4; ++hh)
            tot += (parts[hh][i >> 5] >> (i & 31)) & 1;
        pc[((size_t)g * 256 + n) * 128 + i] = (unsigned char)tot;
    }
}

__global__ __launch_bounds__(128) void vote_kernel(
    const unsigned char* __restrict__ pc,  // [4][256][128]
    int* __restrict__ out)                 // [S,B]
{
    const int n = blockIdx.x;              // 0..255
    const int i = threadIdx.x;             // 0..127
    int tot = pc[(size_t)(0 * 256 + n) * 128 + i]
            + pc[(size_t)(1 * 256 + n) * 128 + i]
            + pc[(size_t)(2 * 256 + n) * 128 + i]
            + pc[(size_t)(3 * 256 + n) * 128 + i];
    out[i * B + n] = (tot > (H / 2)) ? 1 : 0;
}

extern "C" void kernel_launch(void* const* d_in, const int* in_sizes, int n_in,
                              void* d_out, int out_size, void* d_ws, size_t ws_size,
                              hipStream_t stream) {
    const int*   tokens      = (const int*)d_in[0];
    const float* memory      = (const float*)d_in[1];
    const int*   connections = (const int*)d_in[2];
    int*         out         = (int*)d_out;
    unsigned char* pc        = (unsigned char*)d_ws;              // 128 KB
    unsigned*      tokP      = (unsigned*)((char*)d_ws + 4 * 256 * 128);  // 4 KB
    (void)in_sizes; (void)n_in; (void)out_size; (void)ws_size;

    pack_kernel<<<8, 256, 0, stream>>>(tokens, tokP);
    softram_kernel<<<4 * B, 256, 0, stream>>>(tokP, memory, connections, pc);
    vote_kernel<<<B, 128, 0, stream>>>(pc, out);
}